// Round 1
// baseline (2628.218 us; speedup 1.0000x reference)
//
#include <hip/hip_runtime.h>
#include <math.h>

#define BATCH 4
#define SEQ   4096
#define DM    1024
#define NS    128
#define BS    (BATCH * SEQ)   // 16384 rows

#define MT2 32   // k_bt M-tile
#define KT2 32   // k_bt K-tile
#define MT4 16   // k_out M-tile

__device__ __forceinline__ float sigmoidf_(float z) {
  return 1.0f / (1.0f + __expf(-z));
}

// ---------------------------------------------------------------------------
// K0: transpose W_B [N,D] -> wbt [D,N]   and   W_C [D,N] -> wct [N,D]
// grid 512 x 256 = 131072 threads, one element of each per thread
// ---------------------------------------------------------------------------
__global__ __launch_bounds__(256) void k_prep(const float* __restrict__ W_B,
                                              const float* __restrict__ W_C,
                                              float* __restrict__ wbt,
                                              float* __restrict__ wct) {
  int id = blockIdx.x * 256 + threadIdx.x;   // 0..131071
  {
    int k = id >> 7, n = id & 127;           // wbt[k*128+n] = W_B[n*1024+k]
    wbt[id] = W_B[(size_t)n * DM + k];
  }
  {
    int n = id >> 10, d = id & 1023;         // wct[n*1024+d] = W_C[d*128+n]
    wct[id] = W_C[(size_t)d * NS + n];
  }
}

// ---------------------------------------------------------------------------
// K2: Bt[m,n] = sigmoid( dot(emb[tok[m],:], W_B[n,:]) )
// block = 256 thr, tile 32(M) x 128(N), K staged in 32-chunks via LDS
// ---------------------------------------------------------------------------
__global__ __launch_bounds__(256) void k_bt(const int* __restrict__ tokens,
                                            const float* __restrict__ emb,
                                            const float* __restrict__ wbt,
                                            float* __restrict__ Bt) {
  __shared__ float xs[KT2][MT2 + 4];   // [k][m], pad 36 words: 16B-aligned rows, no write conflicts
  __shared__ float bsm[KT2][NS];       // [k][n]
  __shared__ int toks[MT2];
  const int t = threadIdx.x;
  const int m0 = blockIdx.x * MT2;
  if (t < MT2) toks[t] = tokens[m0 + t];
  __syncthreads();

  const int tn = t & 31;               // n-quad index
  const int tm = t >> 5;               // m-quad index (0..7)
  const int row = t >> 3;              // staging row (0..31)
  const int kk = (t & 7) * 4;          // staging k offset
  const size_t xbase = (size_t)toks[row] * DM;

  float4 acc0 = {0,0,0,0}, acc1 = {0,0,0,0}, acc2 = {0,0,0,0}, acc3 = {0,0,0,0};

  for (int k0 = 0; k0 < DM; k0 += KT2) {
    float4 v = *(const float4*)&emb[xbase + k0 + kk];
    xs[kk + 0][row] = v.x;
    xs[kk + 1][row] = v.y;
    xs[kk + 2][row] = v.z;
    xs[kk + 3][row] = v.w;
#pragma unroll
    for (int i = 0; i < 4; i++) {
      int k2 = (t >> 5) + 8 * i;
      *(float4*)&bsm[k2][tn * 4] =
          *(const float4*)&wbt[(size_t)(k0 + k2) * NS + tn * 4];
    }
    __syncthreads();
#pragma unroll 8
    for (int k = 0; k < KT2; k++) {
      float4 av = *(const float4*)&xs[k][tm * 4];
      float4 bv = *(const float4*)&bsm[k][tn * 4];
      acc0.x += av.x * bv.x; acc0.y += av.x * bv.y; acc0.z += av.x * bv.z; acc0.w += av.x * bv.w;
      acc1.x += av.y * bv.x; acc1.y += av.y * bv.y; acc1.z += av.y * bv.z; acc1.w += av.y * bv.w;
      acc2.x += av.z * bv.x; acc2.y += av.z * bv.y; acc2.z += av.z * bv.z; acc2.w += av.z * bv.w;
      acc3.x += av.w * bv.x; acc3.y += av.w * bv.y; acc3.z += av.w * bv.z; acc3.w += av.w * bv.w;
    }
    __syncthreads();
  }

  const size_t ob = (size_t)(m0 + tm * 4) * NS + tn * 4;
  float4 o;
  o.x = sigmoidf_(acc0.x); o.y = sigmoidf_(acc0.y); o.z = sigmoidf_(acc0.z); o.w = sigmoidf_(acc0.w);
  *(float4*)&Bt[ob + 0 * NS] = o;
  o.x = sigmoidf_(acc1.x); o.y = sigmoidf_(acc1.y); o.z = sigmoidf_(acc1.z); o.w = sigmoidf_(acc1.w);
  *(float4*)&Bt[ob + 1 * NS] = o;
  o.x = sigmoidf_(acc2.x); o.y = sigmoidf_(acc2.y); o.z = sigmoidf_(acc2.z); o.w = sigmoidf_(acc2.w);
  *(float4*)&Bt[ob + 2 * NS] = o;
  o.x = sigmoidf_(acc3.x); o.y = sigmoidf_(acc3.y); o.z = sigmoidf_(acc3.z); o.w = sigmoidf_(acc3.w);
  *(float4*)&Bt[ob + 3 * NS] = o;
}

// ---------------------------------------------------------------------------
// K3: the scan. grid = B * (D/8) = 512 wgs, block 256 (4 waves).
// wave w: n = 32w + (l&31); lane half (l>>5) owns d-quad (d0 + 4*(l>>5)).
// h[j] = a[j]*h[j] + bt*x[j]; partial d-sum reduced via shfl_xor(32) and
// atomically added into hm[b,s,n] (hm pre-zeroed).
// ---------------------------------------------------------------------------
__global__ __launch_bounds__(256) void k_scan(const int* __restrict__ tokens,
                                              const float* __restrict__ emb,
                                              const float* __restrict__ A_log,
                                              const float* __restrict__ Bt,
                                              float* __restrict__ hm) {
  __shared__ int toks[SEQ];   // 16 KB
  const int t = threadIdx.x;
  const int b = blockIdx.x >> 7;
  const int dblk = blockIdx.x & 127;
  const int d0 = dblk * 8;
  const int w = t >> 6, l = t & 63;
  const int n = w * 32 + (l & 31);
  const int dbase = d0 + (l >> 5) * 4;

  float a[4], h[4];
#pragma unroll
  for (int j = 0; j < 4; j++) {
    a[j] = sigmoidf_(A_log[(size_t)(dbase + j) * NS + n]);
    h[j] = 0.0f;
  }
  for (int i = t; i < SEQ; i += 256) toks[i] = tokens[b * SEQ + i];
  __syncthreads();

  const float* btb = Bt + (size_t)b * SEQ * NS + n;
  float* hmb = hm + (size_t)b * SEQ * NS + n;

  float4 xq[4]; float bq[4];
#pragma unroll
  for (int u = 0; u < 4; u++) {
    xq[u] = *(const float4*)&emb[(size_t)toks[u] * DM + dbase];
    bq[u] = btb[(size_t)u * NS];
  }

  for (int s4 = 0; s4 < SEQ; s4 += 4) {
#pragma unroll
    for (int u = 0; u < 4; u++) {
      const int s = s4 + u;
      const float4 xv = xq[u];
      const float bv = bq[u];
      const int sp = s + 4;
      if (sp < SEQ) {
        xq[u] = *(const float4*)&emb[(size_t)toks[sp] * DM + dbase];
        bq[u] = btb[(size_t)sp * NS];
      }
      h[0] = a[0] * h[0] + bv * xv.x;
      h[1] = a[1] * h[1] + bv * xv.y;
      h[2] = a[2] * h[2] + bv * xv.z;
      h[3] = a[3] * h[3] + bv * xv.w;
      float s0 = (h[0] + h[1]) + (h[2] + h[3]);
      s0 += __shfl_xor(s0, 32);
      if (l < 32) atomicAdd(&hmb[(size_t)s * NS], s0 * (1.0f / (float)DM));
    }
  }
}

// ---------------------------------------------------------------------------
// K4: y[m,d] = sum_n hm[m,n]*W_C[d,n] + D[d]*x[m,d]; RMSNorm over d; write out.
// block = 256 thr handles 16 rows x 1024 d (thread owns a d-quad).
// ---------------------------------------------------------------------------
__global__ __launch_bounds__(256) void k_out(const int* __restrict__ tokens,
                                             const float* __restrict__ emb,
                                             const float* __restrict__ wct,
                                             const float* __restrict__ hm,
                                             const float* __restrict__ D_param,
                                             const float* __restrict__ norm_w,
                                             float* __restrict__ out) {
  __shared__ float hs[MT4][NS];   // 8 KB
  __shared__ int toks[MT4];
  __shared__ float red[MT4][4];
  __shared__ float scl[MT4];
  const int t = threadIdx.x;
  const int m0 = blockIdx.x * MT4;
  if (t < MT4) toks[t] = tokens[m0 + t];
  {
    float* hsf = &hs[0][0];
    const float* src = hm + (size_t)m0 * NS;
    *(float4*)&hsf[t * 4] = *(const float4*)&src[t * 4];
    *(float4*)&hsf[1024 + t * 4] = *(const float4*)&src[1024 + t * 4];
  }
  __syncthreads();

  const int d4 = t * 4;
  float4 acc[MT4];
#pragma unroll
  for (int r = 0; r < MT4; r++) acc[r] = make_float4(0.f, 0.f, 0.f, 0.f);

#pragma unroll 2
  for (int n = 0; n < NS; n++) {
    float4 wv = *(const float4*)&wct[(size_t)n * DM + d4];
#pragma unroll
    for (int r = 0; r < MT4; r++) {
      float hv = hs[r][n];
      acc[r].x += hv * wv.x; acc[r].y += hv * wv.y;
      acc[r].z += hv * wv.z; acc[r].w += hv * wv.w;
    }
  }

  float4 dp = *(const float4*)&D_param[d4];
#pragma unroll
  for (int r = 0; r < MT4; r++) {
    float4 xv = *(const float4*)&emb[(size_t)toks[r] * DM + d4];
    acc[r].x += dp.x * xv.x; acc[r].y += dp.y * xv.y;
    acc[r].z += dp.z * xv.z; acc[r].w += dp.w * xv.w;
  }

  const int lane = t & 63, wid = t >> 6;
#pragma unroll
  for (int r = 0; r < MT4; r++) {
    float ss = acc[r].x * acc[r].x + acc[r].y * acc[r].y +
               acc[r].z * acc[r].z + acc[r].w * acc[r].w;
    ss += __shfl_xor(ss, 32); ss += __shfl_xor(ss, 16); ss += __shfl_xor(ss, 8);
    ss += __shfl_xor(ss, 4);  ss += __shfl_xor(ss, 2);  ss += __shfl_xor(ss, 1);
    if (lane == 0) red[r][wid] = ss;
  }
  __syncthreads();
  if (t < MT4) {
    float s = red[t][0] + red[t][1] + red[t][2] + red[t][3];
    scl[t] = rsqrtf(s * (1.0f / (float)DM) + 1.1920929e-07f);
  }
  __syncthreads();

  float4 nw = *(const float4*)&norm_w[d4];
#pragma unroll
  for (int r = 0; r < MT4; r++) {
    float sc = scl[r];
    float4 o;
    o.x = acc[r].x * sc * nw.x; o.y = acc[r].y * sc * nw.y;
    o.z = acc[r].z * sc * nw.z; o.w = acc[r].w * sc * nw.w;
    *(float4*)&out[(size_t)(m0 + r) * DM + d4] = o;
  }
}

// ---------------------------------------------------------------------------
extern "C" void kernel_launch(void* const* d_in, const int* in_sizes, int n_in,
                              void* d_out, int out_size, void* d_ws, size_t ws_size,
                              hipStream_t stream) {
  const int*   tokens = (const int*)  d_in[0];
  const float* emb    = (const float*)d_in[1];
  const float* A_log  = (const float*)d_in[2];
  const float* W_B    = (const float*)d_in[3];
  const float* W_C    = (const float*)d_in[4];
  const float* D_p    = (const float*)d_in[5];
  const float* nw     = (const float*)d_in[6];
  float* out = (float*)d_out;

  // workspace layout (all fp32): Bt [BS,NS] | hm [BS,NS] | wbt [DM,NS] | wct [NS,DM]
  float* Bt  = (float*)d_ws;
  float* hm  = Bt  + (size_t)BS * NS;
  float* wbt = hm  + (size_t)BS * NS;
  float* wct = wbt + (size_t)DM * NS;

  k_prep<<<512, 256, 0, stream>>>(W_B, W_C, wbt, wct);
  k_bt<<<BS / MT2, 256, 0, stream>>>(tokens, emb, wbt, Bt);
  hipMemsetAsync(hm, 0, (size_t)BS * NS * sizeof(float), stream);
  k_scan<<<BATCH * (DM / 8), 256, 0, stream>>>(tokens, emb, A_log, Bt, hm);
  k_out<<<BS / MT4, 256, 0, stream>>>(tokens, emb, wct, hm, D_p, nw, out);
}

// Round 2
// 1015.525 us; speedup vs baseline: 2.5880x; 2.5880x over previous
//
#include <hip/hip_runtime.h>
#include <math.h>

#define BATCH 4
#define SEQ   4096
#define DM    1024
#define NS    128
#define BS    (BATCH * SEQ)   // 16384 rows

#define CHUNK  128            // steps per chunk
#define NCHUNK 32             // SEQ / CHUNK
#define GD     8              // d-groups
#define DPG    128            // DM / GD
#define REG    (DPG * NS)     // 16384 floats per (b,c,g) state region

#define MT2 32   // k_bt M-tile
#define KT2 32   // k_bt K-tile
#define MT4 16   // k_out M-tile

__device__ __forceinline__ float sigmoidf_(float z) {
  return 1.0f / (1.0f + __expf(-z));
}

// ---------------------------------------------------------------------------
// K0: transpose W_B [N,D] -> wbt [D,N]   and   W_C [D,N] -> wct [N,D]
// ---------------------------------------------------------------------------
__global__ __launch_bounds__(256) void k_prep(const float* __restrict__ W_B,
                                              const float* __restrict__ W_C,
                                              float* __restrict__ wbt,
                                              float* __restrict__ wct) {
  int id = blockIdx.x * 256 + threadIdx.x;   // 0..131071
  {
    int k = id >> 7, n = id & 127;
    wbt[id] = W_B[(size_t)n * DM + k];
  }
  {
    int n = id >> 10, d = id & 1023;
    wct[id] = W_C[(size_t)d * NS + n];
  }
}

// ---------------------------------------------------------------------------
// K1: Bt[m,n] = sigmoid( dot(emb[tok[m],:], W_B[n,:]) )
// ---------------------------------------------------------------------------
__global__ __launch_bounds__(256) void k_bt(const int* __restrict__ tokens,
                                            const float* __restrict__ emb,
                                            const float* __restrict__ wbt,
                                            float* __restrict__ Bt) {
  __shared__ float xs[KT2][MT2 + 4];
  __shared__ float bsm[KT2][NS];
  __shared__ int toks[MT2];
  const int t = threadIdx.x;
  const int m0 = blockIdx.x * MT2;
  if (t < MT2) toks[t] = tokens[m0 + t];
  __syncthreads();

  const int tn = t & 31;
  const int tm = t >> 5;
  const int row = t >> 3;
  const int kk = (t & 7) * 4;
  const size_t xbase = (size_t)toks[row] * DM;

  float4 acc0 = {0,0,0,0}, acc1 = {0,0,0,0}, acc2 = {0,0,0,0}, acc3 = {0,0,0,0};

  for (int k0 = 0; k0 < DM; k0 += KT2) {
    float4 v = *(const float4*)&emb[xbase + k0 + kk];
    xs[kk + 0][row] = v.x;
    xs[kk + 1][row] = v.y;
    xs[kk + 2][row] = v.z;
    xs[kk + 3][row] = v.w;
#pragma unroll
    for (int i = 0; i < 4; i++) {
      int k2 = (t >> 5) + 8 * i;
      *(float4*)&bsm[k2][tn * 4] =
          *(const float4*)&wbt[(size_t)(k0 + k2) * NS + tn * 4];
    }
    __syncthreads();
#pragma unroll 8
    for (int k = 0; k < KT2; k++) {
      float4 av = *(const float4*)&xs[k][tm * 4];
      float4 bv = *(const float4*)&bsm[k][tn * 4];
      acc0.x += av.x * bv.x; acc0.y += av.x * bv.y; acc0.z += av.x * bv.z; acc0.w += av.x * bv.w;
      acc1.x += av.y * bv.x; acc1.y += av.y * bv.y; acc1.z += av.y * bv.z; acc1.w += av.y * bv.w;
      acc2.x += av.z * bv.x; acc2.y += av.z * bv.y; acc2.z += av.z * bv.z; acc2.w += av.z * bv.w;
      acc3.x += av.w * bv.x; acc3.y += av.w * bv.y; acc3.z += av.w * bv.z; acc3.w += av.w * bv.w;
    }
    __syncthreads();
  }

  const size_t ob = (size_t)(m0 + tm * 4) * NS + tn * 4;
  float4 o;
  o.x = sigmoidf_(acc0.x); o.y = sigmoidf_(acc0.y); o.z = sigmoidf_(acc0.z); o.w = sigmoidf_(acc0.w);
  *(float4*)&Bt[ob + 0 * NS] = o;
  o.x = sigmoidf_(acc1.x); o.y = sigmoidf_(acc1.y); o.z = sigmoidf_(acc1.z); o.w = sigmoidf_(acc1.w);
  *(float4*)&Bt[ob + 1 * NS] = o;
  o.x = sigmoidf_(acc2.x); o.y = sigmoidf_(acc2.y); o.z = sigmoidf_(acc2.z); o.w = sigmoidf_(acc2.w);
  *(float4*)&Bt[ob + 2 * NS] = o;
  o.x = sigmoidf_(acc3.x); o.y = sigmoidf_(acc3.y); o.z = sigmoidf_(acc3.z); o.w = sigmoidf_(acc3.w);
  *(float4*)&Bt[ob + 3 * NS] = o;
}

// ---------------------------------------------------------------------------
// K2/K4: chunked scan worker. blockIdx = (b*32 + c)*8 + g.
// Thread (dsub = t&7, nq = t>>3) owns 16 d x 4 n states in registers.
// EMIT=false: local scan from h=0, store chunk-end state (phase A).
// EMIT=true : scan from h_start (in h_end buffer), emit d-partial means
//             via shfl-reduce + atomicAdd into hm (phase C).
// x-tile in LDS is XOR-swizzled (chunk p = q ^ (q>>2)) so the 16-float
// strided per-thread reads are bank-conflict-free.
// ---------------------------------------------------------------------------
template <bool EMIT>
__global__ __launch_bounds__(256, 2) void k_scan_chunk(
    const int* __restrict__ tokens, const float* __restrict__ emb,
    const float* __restrict__ A_log, const float* __restrict__ Bt,
    float* __restrict__ h_end, float* __restrict__ hm) {
  __shared__ float xs[2][16][128];
  __shared__ float bts[2][16][128];
  __shared__ int toks[CHUNK];
  const int t = threadIdx.x;
  const int g = blockIdx.x & 7;
  const int c = (blockIdx.x >> 3) & 31;
  const int b = blockIdx.x >> 8;
  const int dsub = t & 7;
  const int nq = t >> 3;
  const int s0 = c * CHUNK;

  if (t < CHUNK) toks[t] = tokens[b * SEQ + s0 + t];

  const int dbase = g * DPG + dsub * 16;
  const int nbase = nq * 4;

  float4 a4[16], h4[16];
#pragma unroll
  for (int v = 0; v < 16; v++) {
    float4 al = *(const float4*)&A_log[(size_t)(dbase + v) * NS + nbase];
    a4[v].x = sigmoidf_(al.x); a4[v].y = sigmoidf_(al.y);
    a4[v].z = sigmoidf_(al.z); a4[v].w = sigmoidf_(al.w);
  }
  const size_t hbase = (size_t)blockIdx.x * REG;
  if (EMIT) {
#pragma unroll
    for (int v = 0; v < 16; v++)
      h4[v] = *(const float4*)&h_end[hbase + (size_t)(v * 256 + t) * 4];
  } else {
#pragma unroll
    for (int v = 0; v < 16; v++) h4[v] = make_float4(0.f, 0.f, 0.f, 0.f);
  }

  // swizzled x-read float offsets for this thread's 4 chunks
  int px[4];
#pragma unroll
  for (int j = 0; j < 4; j++) px[j] = (((dsub * 4 + j) ^ dsub) & 31) * 4;

  // staging role: row si (0..15), column quad qq (0..15)
  const int si = t >> 4;
  const int qq = t & 15;
  const int p0 = ((qq ^ (qq >> 2)) & 31) * 4;
  const int p1 = (((qq + 16) ^ ((qq + 16) >> 2)) & 31) * 4;

  __syncthreads();   // toks visible

  // pre-stage tile 0
  {
    const int tok = toks[si];
    const float* xr = &emb[(size_t)tok * DM + g * DPG];
    float4 xa = *(const float4*)&xr[qq * 4];
    float4 xb = *(const float4*)&xr[64 + qq * 4];
    const float* br = &Bt[(size_t)(b * SEQ + s0 + si) * NS];
    float4 ba = *(const float4*)&br[qq * 4];
    float4 bb = *(const float4*)&br[64 + qq * 4];
    *(float4*)&xs[0][si][p0] = xa;
    *(float4*)&xs[0][si][p1] = xb;
    *(float4*)&bts[0][si][qq * 4] = ba;
    *(float4*)&bts[0][si][64 + qq * 4] = bb;
  }

  float* hmp = EMIT ? &hm[(size_t)(b * SEQ + s0) * NS + nbase] : nullptr;
  const float iscale = 1.0f / (float)DM;

  for (int tl = 0; tl < 8; tl++) {
    const int cb = tl & 1;
    float4 xa, xb, ba, bb;
    if (tl < 7) {                       // prefetch next tile into registers
      const int row = (tl + 1) * 16 + si;
      const int tok = toks[row];
      const float* xr = &emb[(size_t)tok * DM + g * DPG];
      xa = *(const float4*)&xr[qq * 4];
      xb = *(const float4*)&xr[64 + qq * 4];
      const float* br = &Bt[(size_t)(b * SEQ + s0 + row) * NS];
      ba = *(const float4*)&br[qq * 4];
      bb = *(const float4*)&br[64 + qq * 4];
    }
    __syncthreads();                    // tile tl writes visible everywhere

#pragma unroll 4
    for (int i = 0; i < 16; i++) {
      float4 bt4 = *(const float4*)&bts[cb][i][nq * 4];
      float4 sm = make_float4(0.f, 0.f, 0.f, 0.f);
#pragma unroll
      for (int j = 0; j < 4; j++) {
        float4 xq = *(const float4*)&xs[cb][i][px[j]];
#define STEP(E, XC)                                                      \
        {                                                                \
          const int v = j * 4 + E;                                       \
          h4[v].x = fmaf(a4[v].x, h4[v].x, bt4.x * (XC));                \
          h4[v].y = fmaf(a4[v].y, h4[v].y, bt4.y * (XC));                \
          h4[v].z = fmaf(a4[v].z, h4[v].z, bt4.z * (XC));                \
          h4[v].w = fmaf(a4[v].w, h4[v].w, bt4.w * (XC));                \
          if (EMIT) {                                                    \
            sm.x += h4[v].x; sm.y += h4[v].y;                            \
            sm.z += h4[v].z; sm.w += h4[v].w;                            \
          }                                                              \
        }
        STEP(0, xq.x) STEP(1, xq.y) STEP(2, xq.z) STEP(3, xq.w)
#undef STEP
      }
      if (EMIT) {
        sm.x += __shfl_xor(sm.x, 1); sm.y += __shfl_xor(sm.y, 1);
        sm.z += __shfl_xor(sm.z, 1); sm.w += __shfl_xor(sm.w, 1);
        sm.x += __shfl_xor(sm.x, 2); sm.y += __shfl_xor(sm.y, 2);
        sm.z += __shfl_xor(sm.z, 2); sm.w += __shfl_xor(sm.w, 2);
        sm.x += __shfl_xor(sm.x, 4); sm.y += __shfl_xor(sm.y, 4);
        sm.z += __shfl_xor(sm.z, 4); sm.w += __shfl_xor(sm.w, 4);
        if (dsub == 0) {
          float* p = hmp + (size_t)(tl * 16 + i) * NS;
          atomicAdd(p + 0, sm.x * iscale);
          atomicAdd(p + 1, sm.y * iscale);
          atomicAdd(p + 2, sm.z * iscale);
          atomicAdd(p + 3, sm.w * iscale);
        }
      }
    }

    if (tl < 7) {                       // write prefetched tile to other buffer
      const int wb = cb ^ 1;
      *(float4*)&xs[wb][si][p0] = xa;
      *(float4*)&xs[wb][si][p1] = xb;
      *(float4*)&bts[wb][si][qq * 4] = ba;
      *(float4*)&bts[wb][si][64 + qq * 4] = bb;
    }
  }

  if (!EMIT) {
#pragma unroll
    for (int v = 0; v < 16; v++)
      *(float4*)&h_end[hbase + (size_t)(v * 256 + t) * 4] = h4[v];
  }
}

// ---------------------------------------------------------------------------
// K3: chunk-carry scan (phase B). In-place on h_end: on entry h_end[b,c] is
// the zero-init local chunk-end state e[c]; on exit it is h_start[c].
// h_start[0]=0; h_start[c] = a^128 * h_start[c-1] + e[c-1].
// ---------------------------------------------------------------------------
__global__ __launch_bounds__(256) void k_carry(const float* __restrict__ A_log,
                                               float* __restrict__ h_end) {
  const int tid = blockIdx.x * 256 + threadIdx.x;   // 0..131071
  const int g = tid >> 14;
  const int o = tid & (REG - 1);
  const int k = o & 3;
  const int tt = (o >> 2) & 255;
  const int v = o >> 10;
  const int dsub = tt & 7, nq = tt >> 3;
  const int d = g * DPG + dsub * 16 + v;
  const int n = nq * 4 + k;
  const float a = sigmoidf_(A_log[(size_t)d * NS + n]);
  float aL = a;
#pragma unroll
  for (int q = 0; q < 7; q++) aL = aL * aL;   // a^128

  for (int b = 0; b < BATCH; b++) {
    float h = 0.f;
    const size_t base = ((size_t)b * 256 + g) * REG + o;
#pragma unroll 8
    for (int c = 0; c < NCHUNK; c++) {
      const size_t idx = base + (size_t)c * 8 * REG;
      const float e = h_end[idx];
      h_end[idx] = h;
      h = fmaf(aL, h, e);
    }
  }
}

// ---------------------------------------------------------------------------
// K5: y[m,d] = sum_n hm[m,n]*W_C[d,n] + D[d]*x[m,d]; RMSNorm over d.
// ---------------------------------------------------------------------------
__global__ __launch_bounds__(256) void k_out(const int* __restrict__ tokens,
                                             const float* __restrict__ emb,
                                             const float* __restrict__ wct,
                                             const float* __restrict__ hm,
                                             const float* __restrict__ D_param,
                                             const float* __restrict__ norm_w,
                                             float* __restrict__ out) {
  __shared__ float hs[MT4][NS];
  __shared__ int toks[MT4];
  __shared__ float red[MT4][4];
  __shared__ float scl[MT4];
  const int t = threadIdx.x;
  const int m0 = blockIdx.x * MT4;
  if (t < MT4) toks[t] = tokens[m0 + t];
  {
    float* hsf = &hs[0][0];
    const float* src = hm + (size_t)m0 * NS;
    *(float4*)&hsf[t * 4] = *(const float4*)&src[t * 4];
    *(float4*)&hsf[1024 + t * 4] = *(const float4*)&src[1024 + t * 4];
  }
  __syncthreads();

  const int d4 = t * 4;
  float4 acc[MT4];
#pragma unroll
  for (int r = 0; r < MT4; r++) acc[r] = make_float4(0.f, 0.f, 0.f, 0.f);

#pragma unroll 2
  for (int n = 0; n < NS; n++) {
    float4 wv = *(const float4*)&wct[(size_t)n * DM + d4];
#pragma unroll
    for (int r = 0; r < MT4; r++) {
      float hv = hs[r][n];
      acc[r].x += hv * wv.x; acc[r].y += hv * wv.y;
      acc[r].z += hv * wv.z; acc[r].w += hv * wv.w;
    }
  }

  float4 dp = *(const float4*)&D_param[d4];
#pragma unroll
  for (int r = 0; r < MT4; r++) {
    float4 xv = *(const float4*)&emb[(size_t)toks[r] * DM + d4];
    acc[r].x += dp.x * xv.x; acc[r].y += dp.y * xv.y;
    acc[r].z += dp.z * xv.z; acc[r].w += dp.w * xv.w;
  }

  const int lane = t & 63, wid = t >> 6;
#pragma unroll
  for (int r = 0; r < MT4; r++) {
    float ss = acc[r].x * acc[r].x + acc[r].y * acc[r].y +
               acc[r].z * acc[r].z + acc[r].w * acc[r].w;
    ss += __shfl_xor(ss, 32); ss += __shfl_xor(ss, 16); ss += __shfl_xor(ss, 8);
    ss += __shfl_xor(ss, 4);  ss += __shfl_xor(ss, 2);  ss += __shfl_xor(ss, 1);
    if (lane == 0) red[r][wid] = ss;
  }
  __syncthreads();
  if (t < MT4) {
    float s = red[t][0] + red[t][1] + red[t][2] + red[t][3];
    scl[t] = rsqrtf(s * (1.0f / (float)DM) + 1.1920929e-07f);
  }
  __syncthreads();

  float4 nw = *(const float4*)&norm_w[d4];
#pragma unroll
  for (int r = 0; r < MT4; r++) {
    float sc = scl[r];
    float4 o;
    o.x = acc[r].x * sc * nw.x; o.y = acc[r].y * sc * nw.y;
    o.z = acc[r].z * sc * nw.z; o.w = acc[r].w * sc * nw.w;
    *(float4*)&out[(size_t)(m0 + r) * DM + d4] = o;
  }
}

// ---------------------------------------------------------------------------
extern "C" void kernel_launch(void* const* d_in, const int* in_sizes, int n_in,
                              void* d_out, int out_size, void* d_ws, size_t ws_size,
                              hipStream_t stream) {
  const int*   tokens = (const int*)  d_in[0];
  const float* emb    = (const float*)d_in[1];
  const float* A_log  = (const float*)d_in[2];
  const float* W_B    = (const float*)d_in[3];
  const float* W_C    = (const float*)d_in[4];
  const float* D_p    = (const float*)d_in[5];
  const float* nw     = (const float*)d_in[6];
  float* out = (float*)d_out;

  // workspace: Bt [BS,NS] | hm [BS,NS] | wbt [DM,NS] | wct [NS,DM] | h_end
  float* Bt    = (float*)d_ws;
  float* hm    = Bt  + (size_t)BS * NS;
  float* wbt   = hm  + (size_t)BS * NS;
  float* wct   = wbt + (size_t)DM * NS;
  float* h_end = wct + (size_t)DM * NS;   // BATCH*NCHUNK*GD*REG = 16.78M floats

  k_prep<<<512, 256, 0, stream>>>(W_B, W_C, wbt, wct);
  k_bt<<<BS / MT2, 256, 0, stream>>>(tokens, emb, wbt, Bt);
  k_scan_chunk<false><<<BATCH * NCHUNK * GD, 256, 0, stream>>>(
      tokens, emb, A_log, Bt, h_end, nullptr);
  k_carry<<<(DM * NS) / 256, 256, 0, stream>>>(A_log, h_end);
  hipMemsetAsync(hm, 0, (size_t)BS * NS * sizeof(float), stream);
  k_scan_chunk<true><<<BATCH * NCHUNK * GD, 256, 0, stream>>>(
      tokens, emb, A_log, Bt, h_end, hm);
  k_out<<<BS / MT4, 256, 0, stream>>>(tokens, emb, wct, hm, D_p, nw, out);
}